// Round 2
// baseline (357.597 us; speedup 1.0000x reference)
//
#include <hip/hip_runtime.h>

// LearnabilityMB: z = sum_i a[i] * y^T U^{i+1} y with U = strict_upper(X diag(s) X^T)
// Implemented as column-wise scans over X (two 2-pass stages), out = 1 - z.
//
// Shapes: X [8192,4096] f32 row-major, s [4096], y [8192], a [4]. out [1].
// (Resubmission: round-1 bench was an infra failure, kernel never ran.)

#define NROWS 8192
#define DCOLS 4096
#define RB    64              // rows per scan block
#define NBLK  (NROWS / RB)    // 128 row blocks
#define CTILE 1024            // columns per workgroup (256 thr * float4)

// ---------------- pass 1: block-partial column sums ----------------
// P0[rb][d] = sum_{n in block rb} X[n][d] * v0[n]
__global__ __launch_bounds__(256) void partial1_kernel(
    const float* __restrict__ X, const float* __restrict__ v0,
    float* __restrict__ P0)
{
    const int rb = blockIdx.x;
    const int c  = blockIdx.y * CTILE + threadIdx.x * 4;
    const int n0 = rb * RB;
    float4 acc = make_float4(0.f, 0.f, 0.f, 0.f);
    #pragma unroll 4
    for (int i = 0; i < RB; ++i) {
        const int n = n0 + i;
        const float4 x = *reinterpret_cast<const float4*>(X + (size_t)n * DCOLS + c);
        const float  a = v0[n];
        acc.x += x.x * a; acc.y += x.y * a; acc.z += x.z * a; acc.w += x.w * a;
    }
    *reinterpret_cast<float4*>(P0 + (size_t)rb * DCOLS + c) = acc;
}

// Same, for two vectors sharing one X read (stage B).
__global__ __launch_bounds__(256) void partial2_kernel(
    const float* __restrict__ X,
    const float* __restrict__ v0, float* __restrict__ P0,
    const float* __restrict__ v1, float* __restrict__ P1)
{
    const int rb = blockIdx.x;
    const int c  = blockIdx.y * CTILE + threadIdx.x * 4;
    const int n0 = rb * RB;
    float4 a0 = make_float4(0.f, 0.f, 0.f, 0.f);
    float4 a1 = make_float4(0.f, 0.f, 0.f, 0.f);
    #pragma unroll 4
    for (int i = 0; i < RB; ++i) {
        const int n = n0 + i;
        const float4 x = *reinterpret_cast<const float4*>(X + (size_t)n * DCOLS + c);
        const float  u = v0[n];
        const float  w = v1[n];
        a0.x += x.x * u; a0.y += x.y * u; a0.z += x.z * u; a0.w += x.w * u;
        a1.x += x.x * w; a1.y += x.y * w; a1.z += x.z * w; a1.w += x.w * w;
    }
    *reinterpret_cast<float4*>(P0 + (size_t)rb * DCOLS + c) = a0;
    *reinterpret_cast<float4*>(P1 + (size_t)rb * DCOLS + c) = a1;
}

// ---------------- block-level exclusive prefix over row blocks ----------------
// In-place: P[rb][c] <- sum_{rb' < rb} P[rb'][c];  Tot[c] = full column sum.
template<int TWO>
__global__ __launch_bounds__(256) void prefix_kernel(
    float* __restrict__ P0, float* __restrict__ Tot0,
    float* __restrict__ P1, float* __restrict__ Tot1)
{
    const int c = blockIdx.x * 256 + threadIdx.x;   // one column per thread
    float run0 = 0.f, run1 = 0.f;
    #pragma unroll 4
    for (int rb = 0; rb < NBLK; ++rb) {
        const size_t idx = (size_t)rb * DCOLS + c;
        const float v0 = P0[idx];
        P0[idx] = run0;
        run0 += v0;
        if (TWO) {
            const float v1 = P1[idx];
            P1[idx] = run1;
            run1 += v1;
        }
    }
    Tot0[c] = run0;
    if (TWO) Tot1[c] = run1;
}

// ---------------- pass 2: scan + per-row dot ----------------
// out_r[n] += sum_c X[n,c]*s[c]*(TotR[c] - Cr[n,c])   (Cr inclusive prefix of X*vr)
// out_l[n] += sum_c X[n,c]*s[c]*Cl[n-1,c]             (Cl exclusive prefix of X*vl)
// Stage A: Pr==Pl==P_y, vr==vl==y. Stage B: vr=r1, vl=l1.
__global__ __launch_bounds__(256) void pass2_kernel(
    const float* __restrict__ X, const float* __restrict__ s,
    const float* __restrict__ Pr, const float* __restrict__ TotR,
    const float* __restrict__ Pl,
    const float* __restrict__ vr, const float* __restrict__ vl,
    float* __restrict__ out_r, float* __restrict__ out_l)
{
    const int rb = blockIdx.x;
    const int c  = blockIdx.y * CTILE + threadIdx.x * 4;
    const size_t pidx = (size_t)rb * DCOLS + c;

    float4 Cr = *reinterpret_cast<const float4*>(Pr + pidx);
    float4 Cl = *reinterpret_cast<const float4*>(Pl + pidx);
    const float4 Tot = *reinterpret_cast<const float4*>(TotR + c);
    const float4 s4  = *reinterpret_cast<const float4*>(s + c);

    const int n0 = rb * RB;
    for (int i = 0; i < RB; ++i) {
        const int n = n0 + i;
        const float4 x = *reinterpret_cast<const float4*>(X + (size_t)n * DCOLS + c);
        const float xs0 = x.x * s4.x, xs1 = x.y * s4.y;
        const float xs2 = x.z * s4.z, xs3 = x.w * s4.w;

        // l-path uses exclusive prefix (before adding row n)
        float lp = xs0 * Cl.x + xs1 * Cl.y + xs2 * Cl.z + xs3 * Cl.w;

        const float ar = vr[n];
        const float al = vl[n];
        Cl.x += x.x * al; Cl.y += x.y * al; Cl.z += x.z * al; Cl.w += x.w * al;
        Cr.x += x.x * ar; Cr.y += x.y * ar; Cr.z += x.z * ar; Cr.w += x.w * ar;

        // r-path uses suffix = Tot - inclusive prefix
        float rp = xs0 * (Tot.x - Cr.x) + xs1 * (Tot.y - Cr.y)
                 + xs2 * (Tot.z - Cr.z) + xs3 * (Tot.w - Cr.w);

        // wave-level reduction, one atomic per wave per row
        #pragma unroll
        for (int o = 32; o > 0; o >>= 1) {
            lp += __shfl_xor(lp, o, 64);
            rp += __shfl_xor(rp, o, 64);
        }
        if ((threadIdx.x & 63) == 0) {
            atomicAdd(out_l + n, lp);
            atomicAdd(out_r + n, rp);
        }
    }
}

// ---------------- final dots ----------------
__global__ __launch_bounds__(256) void finish_kernel(
    const float* __restrict__ y,  const float* __restrict__ r1,
    const float* __restrict__ l1, const float* __restrict__ r2,
    const float* __restrict__ l2, const float* __restrict__ a,
    float* __restrict__ out)
{
    __shared__ float sm[4][4];
    float d0 = 0.f, d1 = 0.f, d2 = 0.f, d3 = 0.f;
    for (int n = threadIdx.x; n < NROWS; n += 256) {
        const float yv = y[n], R1 = r1[n], L1 = l1[n], R2 = r2[n], L2 = l2[n];
        d0 += yv * R1;   // a0: y . r1
        d1 += L1 * R1;   // a1: l1 . r1
        d2 += L1 * R2;   // a2: l1 . r2
        d3 += L2 * R2;   // a3: l2 . r2
    }
    #pragma unroll
    for (int o = 32; o > 0; o >>= 1) {
        d0 += __shfl_xor(d0, o, 64); d1 += __shfl_xor(d1, o, 64);
        d2 += __shfl_xor(d2, o, 64); d3 += __shfl_xor(d3, o, 64);
    }
    const int w = threadIdx.x >> 6;
    if ((threadIdx.x & 63) == 0) { sm[w][0] = d0; sm[w][1] = d1; sm[w][2] = d2; sm[w][3] = d3; }
    __syncthreads();
    if (threadIdx.x == 0) {
        float t0 = 0.f, t1 = 0.f, t2 = 0.f, t3 = 0.f;
        for (int ww = 0; ww < 4; ++ww) {
            t0 += sm[ww][0]; t1 += sm[ww][1]; t2 += sm[ww][2]; t3 += sm[ww][3];
        }
        const float z = a[0] * t0 + a[1] * t1 + a[2] * t2 + a[3] * t3;
        out[0] = 1.0f - z;
    }
}

extern "C" void kernel_launch(void* const* d_in, const int* in_sizes, int n_in,
                              void* d_out, int out_size, void* d_ws, size_t ws_size,
                              hipStream_t stream)
{
    const float* s = (const float*)d_in[0];   // [DCOLS]
    const float* X = (const float*)d_in[1];   // [NROWS, DCOLS]
    const float* y = (const float*)d_in[2];   // [NROWS]
    const float* a = (const float*)d_in[3];   // [4]
    float* out = (float*)d_out;

    // workspace layout
    char* ws = (char*)d_ws;
    const size_t PSZ = (size_t)NBLK * DCOLS * sizeof(float);   // 2 MB each
    float* Py  = (float*)(ws);
    float* Pr  = (float*)(ws + PSZ);
    float* Pl  = (float*)(ws + 2 * PSZ);
    float* ToY = (float*)(ws + 3 * PSZ);
    float* ToR = ToY + DCOLS;
    float* ToL = ToR + DCOLS;
    float* r1  = ToL + DCOLS;
    float* l1  = r1 + NROWS;
    float* r2  = l1 + NROWS;
    float* l2  = r2 + NROWS;

    // zero the atomic accumulators (r1,l1,r2,l2 are contiguous)
    hipMemsetAsync(r1, 0, 4 * (size_t)NROWS * sizeof(float), stream);

    const dim3 blk(256);
    const dim3 gP(NBLK, DCOLS / CTILE);   // 128 x 4
    const dim3 gPre(DCOLS / 256);         // 16

    // ---- stage A: r1 = U y, l1 = U^T y ----
    partial1_kernel<<<gP, blk, 0, stream>>>(X, y, Py);
    prefix_kernel<0><<<gPre, blk, 0, stream>>>(Py, ToY, nullptr, nullptr);
    pass2_kernel<<<gP, blk, 0, stream>>>(X, s, Py, ToY, Py, y, y, r1, l1);

    // ---- stage B: r2 = U r1, l2 = U^T l1 ----
    partial2_kernel<<<gP, blk, 0, stream>>>(X, r1, Pr, l1, Pl);
    prefix_kernel<1><<<gPre, blk, 0, stream>>>(Pr, ToR, Pl, ToL);
    pass2_kernel<<<gP, blk, 0, stream>>>(X, s, Pr, ToR, Pl, r1, l1, r2, l2);

    // ---- dots + output ----
    finish_kernel<<<dim3(1), blk, 0, stream>>>(y, r1, l1, r2, l2, a, out);
}

// Round 6
// 320.877 us; speedup vs baseline: 1.1144x; 1.1144x over previous
//
#include <hip/hip_runtime.h>
#include <hip/hip_bf16.h>

// LearnabilityMB: z = sum_i a[i] * y^T U^{i+1} y, U = strict_upper(X diag(s) X^T)
// Column-scan formulation; X compressed to bf16 after first pass (3% tolerance,
// bf16 error ~0.3%). One block owns a full 32-row x 4096-col stripe so stage-A
// outputs complete per-block (no atomics) and stage-B partials fuse in.
//
// Shapes: X [8192,4096] f32 row-major, s [4096], y [8192], a [4]. out [1].
// (3rd resubmission: rounds 3-5 were infra failures — GPU broker at capacity;
//  ws_size confirmed ~512 MB from round-2 poison-fill WRITE_SIZE, 76 MB used.)

#define NROWS 8192
#define DCOLS 4096
#define RB    32              // rows per stripe
#define NBLK  (NROWS / RB)    // 256 stripes

__device__ inline unsigned short f2bf(float f) {
    __hip_bfloat16 h = __float2bfloat16(f);
    return *reinterpret_cast<unsigned short*>(&h);
}
__device__ inline float bf2f(unsigned short u) {
    return __uint_as_float(((unsigned int)u) << 16);
}
__device__ inline float waveReduce(float v) {
    #pragma unroll
    for (int o = 32; o > 0; o >>= 1) v += __shfl_xor(v, o, 64);
    return v;
}

// ---------------- K1: f32 X -> bf16 Xb, + stage-A block partials ----------------
// Py[rb][d] = sum_{n in stripe rb} bf16(X[n][d]) * y[n]
__global__ __launch_bounds__(256) void k1_conv_partial(
    const float* __restrict__ X, const float* __restrict__ y,
    unsigned short* __restrict__ Xb, float* __restrict__ Py)
{
    __shared__ float yv[RB];
    const int rb = blockIdx.x;
    const int c  = blockIdx.y * 1024 + threadIdx.x * 4;
    const int n0 = rb * RB;
    if (threadIdx.x < RB) yv[threadIdx.x] = y[n0 + threadIdx.x];
    __syncthreads();

    float4 acc = make_float4(0.f, 0.f, 0.f, 0.f);
    #pragma unroll 4
    for (int i = 0; i < RB; ++i) {
        const size_t off = (size_t)(n0 + i) * DCOLS + c;
        const float4 x = *reinterpret_cast<const float4*>(X + off);
        ushort4 u;
        u.x = f2bf(x.x); u.y = f2bf(x.y); u.z = f2bf(x.z); u.w = f2bf(x.w);
        *reinterpret_cast<ushort4*>(Xb + off) = u;
        // accumulate with the ROUNDED values so all passes see the same matrix
        const float a = yv[i];
        acc.x += bf2f(u.x) * a; acc.y += bf2f(u.y) * a;
        acc.z += bf2f(u.z) * a; acc.w += bf2f(u.w) * a;
    }
    *reinterpret_cast<float4*>(Py + (size_t)rb * DCOLS + c) = acc;
}

// ---------------- block-level exclusive prefix over stripes ----------------
template<int TWO>
__global__ __launch_bounds__(256) void prefix_kernel(
    float* __restrict__ P0, float* __restrict__ Tot0,
    float* __restrict__ P1, float* __restrict__ Tot1)
{
    const int c = blockIdx.x * 256 + threadIdx.x;
    float run0 = 0.f, run1 = 0.f;
    #pragma unroll 4
    for (int rb = 0; rb < NBLK; ++rb) {
        const size_t idx = (size_t)rb * DCOLS + c;
        const float v0 = P0[idx];
        P0[idx] = run0;
        run0 += v0;
        if (TWO) {
            const float v1 = P1[idx];
            P1[idx] = run1;
            run1 += v1;
        }
    }
    Tot0[c] = run0;
    if (TWO) Tot1[c] = run1;
}

// ---------------- K3: stage-A pass2 (r1,l1) + fused stage-B partials ----------------
// Block rb owns rows [rb*RB, rb*RB+RB) x all 4096 cols (512 thr x 8 bf16 cols).
// Stage A: vr = vl = y  =>  one scan register set C.
__global__ __launch_bounds__(512) void k3_pass2A_partialB(
    const unsigned short* __restrict__ Xb, const float* __restrict__ s,
    const float* __restrict__ Py, const float* __restrict__ ToY,
    const float* __restrict__ y,
    float* __restrict__ r1, float* __restrict__ l1,
    float* __restrict__ Pr, float* __restrict__ Pl)
{
    __shared__ float yv[RB];
    __shared__ float partR[RB][8];
    __shared__ float partL[RB][8];
    __shared__ float rblk[RB], lblk[RB];

    const int rb = blockIdx.x;
    const int tid = threadIdx.x;
    const int c = tid * 8;
    const int n0 = rb * RB;
    const int wave = tid >> 6;
    if (tid < RB) yv[tid] = y[n0 + tid];
    __syncthreads();

    const size_t pidx = (size_t)rb * DCOLS + c;
    float C[8], Tot[8], sv[8];
    {
        const float4 p0 = *reinterpret_cast<const float4*>(Py + pidx);
        const float4 p1 = *reinterpret_cast<const float4*>(Py + pidx + 4);
        C[0]=p0.x; C[1]=p0.y; C[2]=p0.z; C[3]=p0.w;
        C[4]=p1.x; C[5]=p1.y; C[6]=p1.z; C[7]=p1.w;
        const float4 t0 = *reinterpret_cast<const float4*>(ToY + c);
        const float4 t1 = *reinterpret_cast<const float4*>(ToY + c + 4);
        Tot[0]=t0.x; Tot[1]=t0.y; Tot[2]=t0.z; Tot[3]=t0.w;
        Tot[4]=t1.x; Tot[5]=t1.y; Tot[6]=t1.z; Tot[7]=t1.w;
        const float4 s0 = *reinterpret_cast<const float4*>(s + c);
        const float4 s1 = *reinterpret_cast<const float4*>(s + c + 4);
        sv[0]=s0.x; sv[1]=s0.y; sv[2]=s0.z; sv[3]=s0.w;
        sv[4]=s1.x; sv[5]=s1.y; sv[6]=s1.z; sv[7]=s1.w;
    }

    // ---- phase 1: scan + per-row dots ----
    for (int i = 0; i < RB; ++i) {
        const uint4 ub = *reinterpret_cast<const uint4*>(
            Xb + (size_t)(n0 + i) * DCOLS + c);
        float x[8];
        x[0] = __uint_as_float(ub.x << 16); x[1] = __uint_as_float(ub.x & 0xffff0000u);
        x[2] = __uint_as_float(ub.y << 16); x[3] = __uint_as_float(ub.y & 0xffff0000u);
        x[4] = __uint_as_float(ub.z << 16); x[5] = __uint_as_float(ub.z & 0xffff0000u);
        x[6] = __uint_as_float(ub.w << 16); x[7] = __uint_as_float(ub.w & 0xffff0000u);
        const float av = yv[i];
        float lp = 0.f, rp = 0.f;
        #pragma unroll
        for (int j = 0; j < 8; ++j) {
            const float xs = x[j] * sv[j];
            lp += xs * C[j];            // exclusive prefix (l-path)
            C[j] += x[j] * av;
            rp += xs * (Tot[j] - C[j]); // suffix (r-path)
        }
        lp = waveReduce(lp);
        rp = waveReduce(rp);
        if ((tid & 63) == 0) { partL[i][wave] = lp; partR[i][wave] = rp; }
    }
    __syncthreads();
    if (tid < RB) {
        float rv = 0.f, lv = 0.f;
        #pragma unroll
        for (int w = 0; w < 8; ++w) { rv += partR[tid][w]; lv += partL[tid][w]; }
        r1[n0 + tid] = rv; l1[n0 + tid] = lv;
        rblk[tid] = rv;    lblk[tid] = lv;
    }
    __syncthreads();

    // ---- phase 2: stage-B partials (tile re-read hits L2/L3) ----
    float ar[8], al[8];
    #pragma unroll
    for (int j = 0; j < 8; ++j) { ar[j] = 0.f; al[j] = 0.f; }
    for (int i = 0; i < RB; ++i) {
        const uint4 ub = *reinterpret_cast<const uint4*>(
            Xb + (size_t)(n0 + i) * DCOLS + c);
        float x[8];
        x[0] = __uint_as_float(ub.x << 16); x[1] = __uint_as_float(ub.x & 0xffff0000u);
        x[2] = __uint_as_float(ub.y << 16); x[3] = __uint_as_float(ub.y & 0xffff0000u);
        x[4] = __uint_as_float(ub.z << 16); x[5] = __uint_as_float(ub.z & 0xffff0000u);
        x[6] = __uint_as_float(ub.w << 16); x[7] = __uint_as_float(ub.w & 0xffff0000u);
        const float rv = rblk[i], lv = lblk[i];
        #pragma unroll
        for (int j = 0; j < 8; ++j) { ar[j] += x[j] * rv; al[j] += x[j] * lv; }
    }
    *reinterpret_cast<float4*>(Pr + pidx)     = make_float4(ar[0], ar[1], ar[2], ar[3]);
    *reinterpret_cast<float4*>(Pr + pidx + 4) = make_float4(ar[4], ar[5], ar[6], ar[7]);
    *reinterpret_cast<float4*>(Pl + pidx)     = make_float4(al[0], al[1], al[2], al[3]);
    *reinterpret_cast<float4*>(Pl + pidx + 4) = make_float4(al[4], al[5], al[6], al[7]);
}

// ---------------- K5: stage-B pass2 -> r2, l2 (direct writes) ----------------
__global__ __launch_bounds__(512) void k5_pass2B(
    const unsigned short* __restrict__ Xb, const float* __restrict__ s,
    const float* __restrict__ Pr, const float* __restrict__ ToR,
    const float* __restrict__ Pl,
    const float* __restrict__ r1v, const float* __restrict__ l1v,
    float* __restrict__ r2, float* __restrict__ l2)
{
    __shared__ float rv_s[RB], lv_s[RB];
    __shared__ float partR[RB][8];
    __shared__ float partL[RB][8];

    const int rb = blockIdx.x;
    const int tid = threadIdx.x;
    const int c = tid * 8;
    const int n0 = rb * RB;
    const int wave = tid >> 6;
    if (tid < RB) { rv_s[tid] = r1v[n0 + tid]; lv_s[tid] = l1v[n0 + tid]; }
    __syncthreads();

    const size_t pidx = (size_t)rb * DCOLS + c;
    float Cr[8], Cl[8], Tot[8], sv[8];
    {
        const float4 p0 = *reinterpret_cast<const float4*>(Pr + pidx);
        const float4 p1 = *reinterpret_cast<const float4*>(Pr + pidx + 4);
        Cr[0]=p0.x; Cr[1]=p0.y; Cr[2]=p0.z; Cr[3]=p0.w;
        Cr[4]=p1.x; Cr[5]=p1.y; Cr[6]=p1.z; Cr[7]=p1.w;
        const float4 q0 = *reinterpret_cast<const float4*>(Pl + pidx);
        const float4 q1 = *reinterpret_cast<const float4*>(Pl + pidx + 4);
        Cl[0]=q0.x; Cl[1]=q0.y; Cl[2]=q0.z; Cl[3]=q0.w;
        Cl[4]=q1.x; Cl[5]=q1.y; Cl[6]=q1.z; Cl[7]=q1.w;
        const float4 t0 = *reinterpret_cast<const float4*>(ToR + c);
        const float4 t1 = *reinterpret_cast<const float4*>(ToR + c + 4);
        Tot[0]=t0.x; Tot[1]=t0.y; Tot[2]=t0.z; Tot[3]=t0.w;
        Tot[4]=t1.x; Tot[5]=t1.y; Tot[6]=t1.z; Tot[7]=t1.w;
        const float4 s0 = *reinterpret_cast<const float4*>(s + c);
        const float4 s1 = *reinterpret_cast<const float4*>(s + c + 4);
        sv[0]=s0.x; sv[1]=s0.y; sv[2]=s0.z; sv[3]=s0.w;
        sv[4]=s1.x; sv[5]=s1.y; sv[6]=s1.z; sv[7]=s1.w;
    }

    for (int i = 0; i < RB; ++i) {
        const uint4 ub = *reinterpret_cast<const uint4*>(
            Xb + (size_t)(n0 + i) * DCOLS + c);
        float x[8];
        x[0] = __uint_as_float(ub.x << 16); x[1] = __uint_as_float(ub.x & 0xffff0000u);
        x[2] = __uint_as_float(ub.y << 16); x[3] = __uint_as_float(ub.y & 0xffff0000u);
        x[4] = __uint_as_float(ub.z << 16); x[5] = __uint_as_float(ub.z & 0xffff0000u);
        x[6] = __uint_as_float(ub.w << 16); x[7] = __uint_as_float(ub.w & 0xffff0000u);
        const float rv = rv_s[i], lv = lv_s[i];
        float lp = 0.f, rp = 0.f;
        #pragma unroll
        for (int j = 0; j < 8; ++j) {
            const float xs = x[j] * sv[j];
            lp += xs * Cl[j];            // exclusive prefix of X*l1
            Cl[j] += x[j] * lv;
            Cr[j] += x[j] * rv;
            rp += xs * (Tot[j] - Cr[j]); // suffix of X*r1
        }
        lp = waveReduce(lp);
        rp = waveReduce(rp);
        if ((tid & 63) == 0) { partL[i][wave] = lp; partR[i][wave] = rp; }
    }
    __syncthreads();
    if (tid < RB) {
        float rv = 0.f, lv = 0.f;
        #pragma unroll
        for (int w = 0; w < 8; ++w) { rv += partR[tid][w]; lv += partL[tid][w]; }
        r2[n0 + tid] = rv; l2[n0 + tid] = lv;
    }
}

// ---------------- final dots ----------------
__global__ __launch_bounds__(256) void finish_kernel(
    const float* __restrict__ y,  const float* __restrict__ r1,
    const float* __restrict__ l1, const float* __restrict__ r2,
    const float* __restrict__ l2, const float* __restrict__ a,
    float* __restrict__ out)
{
    __shared__ float sm[4][4];
    float d0 = 0.f, d1 = 0.f, d2 = 0.f, d3 = 0.f;
    for (int n = threadIdx.x; n < NROWS; n += 256) {
        const float yv = y[n], R1 = r1[n], L1 = l1[n], R2 = r2[n], L2 = l2[n];
        d0 += yv * R1;
        d1 += L1 * R1;
        d2 += L1 * R2;
        d3 += L2 * R2;
    }
    d0 = waveReduce(d0); d1 = waveReduce(d1);
    d2 = waveReduce(d2); d3 = waveReduce(d3);
    const int w = threadIdx.x >> 6;
    if ((threadIdx.x & 63) == 0) { sm[w][0] = d0; sm[w][1] = d1; sm[w][2] = d2; sm[w][3] = d3; }
    __syncthreads();
    if (threadIdx.x == 0) {
        float t0 = 0.f, t1 = 0.f, t2 = 0.f, t3 = 0.f;
        for (int ww = 0; ww < 4; ++ww) {
            t0 += sm[ww][0]; t1 += sm[ww][1]; t2 += sm[ww][2]; t3 += sm[ww][3];
        }
        const float z = a[0] * t0 + a[1] * t1 + a[2] * t2 + a[3] * t3;
        out[0] = 1.0f - z;
    }
}

extern "C" void kernel_launch(void* const* d_in, const int* in_sizes, int n_in,
                              void* d_out, int out_size, void* d_ws, size_t ws_size,
                              hipStream_t stream)
{
    const float* s = (const float*)d_in[0];   // [DCOLS]
    const float* X = (const float*)d_in[1];   // [NROWS, DCOLS]
    const float* y = (const float*)d_in[2];   // [NROWS]
    const float* a = (const float*)d_in[3];   // [4]
    float* out = (float*)d_out;

    char* ws = (char*)d_ws;
    const size_t XBSZ = (size_t)NROWS * DCOLS * sizeof(unsigned short);  // 64 MB
    const size_t PCNT = (size_t)NBLK * DCOLS;                            // 1M floats
    unsigned short* Xb = (unsigned short*)ws;
    float* Py  = (float*)(ws + XBSZ);
    float* Pr  = Py + PCNT;
    float* Pl  = Pr + PCNT;
    float* ToY = Pl + PCNT;
    float* ToR = ToY + DCOLS;
    float* ToL = ToR + DCOLS;
    float* r1  = ToL + DCOLS;
    float* l1  = r1 + NROWS;
    float* r2  = l1 + NROWS;
    float* l2  = r2 + NROWS;

    // stage A
    k1_conv_partial<<<dim3(NBLK, 4), dim3(256), 0, stream>>>(X, y, Xb, Py);
    prefix_kernel<0><<<dim3(DCOLS / 256), dim3(256), 0, stream>>>(Py, ToY, nullptr, nullptr);
    k3_pass2A_partialB<<<dim3(NBLK), dim3(512), 0, stream>>>(
        Xb, s, Py, ToY, y, r1, l1, Pr, Pl);

    // stage B
    prefix_kernel<1><<<dim3(DCOLS / 256), dim3(256), 0, stream>>>(Pr, ToR, Pl, ToL);
    k5_pass2B<<<dim3(NBLK), dim3(512), 0, stream>>>(
        Xb, s, Pr, ToR, Pl, r1, l1, r2, l2);

    // dots
    finish_kernel<<<dim3(1), dim3(256), 0, stream>>>(y, r1, l1, r2, l2, a, out);
}

// Round 10
// 307.760 us; speedup vs baseline: 1.1619x; 1.0426x over previous
//
#include <hip/hip_runtime.h>
#include <hip/hip_bf16.h>

// LearnabilityMB: z = sum_i a[i] * y^T U^{i+1} y, U = strict_upper(X diag(s) X^T)
// Column-scan formulation. X compressed once to fp8-e4m3 (error in z ~1e-3 vs
// 1.96e-2 threshold; ref z ~= 0.02). Stage-A pass2 fuses stage-B partials;
// all 4 dot products fused into the scan kernels via device atomics.
//
// Shapes: X [8192,4096] f32 row-major, s [4096], y [8192], a [4]. out [1].
// (Resubmission: rounds 7-9 were GPUAcquisitionTimeouts, kernel never ran.)

#define NROWS 8192
#define DCOLS 4096
#define RB    32              // rows per stripe
#define NBLK  (NROWS / RB)    // 256 stripes

#if defined(__has_builtin)
#if __has_builtin(__builtin_amdgcn_cvt_pk_f32_fp8) && __has_builtin(__builtin_amdgcn_cvt_pk_fp8_f32)
#define XCODEC_FP8 1
#endif
#endif
#ifndef XCODEC_FP8
#define XCODEC_FP8 0
#endif

typedef __attribute__((ext_vector_type(2))) float f32x2;

__device__ inline unsigned short f2bf(float f) {
    __hip_bfloat16 h = __float2bfloat16(f);
    return *reinterpret_cast<unsigned short*>(&h);
}
__device__ inline float bf2f(unsigned short u) {
    return __uint_as_float(((unsigned int)u) << 16);
}
__device__ inline float waveReduce(float v) {
    #pragma unroll
    for (int o = 32; o > 0; o >>= 1) v += __shfl_xor(v, o, 64);
    return v;
}

// store 4 columns at element-offset `off` (multiple of 4) and return DECODED values
__device__ inline void xstore4(unsigned char* Xb, size_t off, const float4& x, float* dec) {
#if XCODEC_FP8
    unsigned int r = __builtin_amdgcn_cvt_pk_fp8_f32(x.x, x.y, 0u, false);
    r = __builtin_amdgcn_cvt_pk_fp8_f32(x.z, x.w, r, true);
    *reinterpret_cast<unsigned int*>(Xb + off) = r;
    const f32x2 d01 = __builtin_amdgcn_cvt_pk_f32_fp8(r, false);
    const f32x2 d23 = __builtin_amdgcn_cvt_pk_f32_fp8(r, true);
    dec[0] = d01.x; dec[1] = d01.y; dec[2] = d23.x; dec[3] = d23.y;
#else
    ushort4 u;
    u.x = f2bf(x.x); u.y = f2bf(x.y); u.z = f2bf(x.z); u.w = f2bf(x.w);
    *reinterpret_cast<ushort4*>(reinterpret_cast<unsigned short*>(Xb) + off) = u;
    dec[0] = bf2f(u.x); dec[1] = bf2f(u.y); dec[2] = bf2f(u.z); dec[3] = bf2f(u.w);
#endif
}

// load+decode 8 columns at element-offset `off` (multiple of 8)
__device__ inline void xload8(const unsigned char* __restrict__ Xb, size_t off, float* x) {
#if XCODEC_FP8
    const uint2 ub = *reinterpret_cast<const uint2*>(Xb + off);
    const f32x2 a = __builtin_amdgcn_cvt_pk_f32_fp8(ub.x, false);
    const f32x2 b = __builtin_amdgcn_cvt_pk_f32_fp8(ub.x, true);
    const f32x2 c = __builtin_amdgcn_cvt_pk_f32_fp8(ub.y, false);
    const f32x2 d = __builtin_amdgcn_cvt_pk_f32_fp8(ub.y, true);
    x[0] = a.x; x[1] = a.y; x[2] = b.x; x[3] = b.y;
    x[4] = c.x; x[5] = c.y; x[6] = d.x; x[7] = d.y;
#else
    const uint4 ub = *reinterpret_cast<const uint4*>(
        reinterpret_cast<const unsigned short*>(Xb) + off);
    x[0] = __uint_as_float(ub.x << 16); x[1] = __uint_as_float(ub.x & 0xffff0000u);
    x[2] = __uint_as_float(ub.y << 16); x[3] = __uint_as_float(ub.y & 0xffff0000u);
    x[4] = __uint_as_float(ub.z << 16); x[5] = __uint_as_float(ub.z & 0xffff0000u);
    x[6] = __uint_as_float(ub.w << 16); x[7] = __uint_as_float(ub.w & 0xffff0000u);
#endif
}

// ---------------- K1: f32 X -> compressed Xb, + stage-A block partials ----------------
// Py[rb][d] = sum_{n in stripe rb} decode(Xb[n][d]) * y[n]
__global__ __launch_bounds__(256) void k1_conv_partial(
    const float* __restrict__ X, const float* __restrict__ y,
    unsigned char* __restrict__ Xb, float* __restrict__ Py)
{
    __shared__ float yv[RB];
    const int rb = blockIdx.x;
    const int c  = blockIdx.y * 1024 + threadIdx.x * 4;
    const int n0 = rb * RB;
    if (threadIdx.x < RB) yv[threadIdx.x] = y[n0 + threadIdx.x];
    __syncthreads();

    float acc[4] = {0.f, 0.f, 0.f, 0.f};
    #pragma unroll 4
    for (int i = 0; i < RB; ++i) {
        const size_t off = (size_t)(n0 + i) * DCOLS + c;
        const float4 x = *reinterpret_cast<const float4*>(X + off);
        float dec[4];
        xstore4(Xb, off, x, dec);
        const float a = yv[i];
        acc[0] += dec[0] * a; acc[1] += dec[1] * a;
        acc[2] += dec[2] * a; acc[3] += dec[3] * a;
    }
    *reinterpret_cast<float4*>(Py + (size_t)rb * DCOLS + c) =
        make_float4(acc[0], acc[1], acc[2], acc[3]);
}

// ---------------- block-level exclusive prefix over stripes ----------------
template<int TWO>
__global__ __launch_bounds__(256) void prefix_kernel(
    float* __restrict__ P0, float* __restrict__ Tot0,
    float* __restrict__ P1, float* __restrict__ Tot1,
    float* __restrict__ dots)
{
    if (!TWO && blockIdx.x == 0 && threadIdx.x < 4) dots[threadIdx.x] = 0.f;
    const int c = blockIdx.x * 256 + threadIdx.x;
    float run0 = 0.f, run1 = 0.f;
    #pragma unroll 4
    for (int rb = 0; rb < NBLK; ++rb) {
        const size_t idx = (size_t)rb * DCOLS + c;
        const float v0 = P0[idx];
        P0[idx] = run0;
        run0 += v0;
        if (TWO) {
            const float v1 = P1[idx];
            P1[idx] = run1;
            run1 += v1;
        }
    }
    Tot0[c] = run0;
    if (TWO) Tot1[c] = run1;
}

// ---------------- K3: stage-A pass2 (r1,l1) + fused stage-B partials + dots d0,d1 ----
// Block rb owns rows [rb*RB, rb*RB+RB) x all 4096 cols (512 thr x 8 cols).
// Stage A: vr = vl = y  =>  one scan register set C.
__global__ __launch_bounds__(512) void k3_pass2A_partialB(
    const unsigned char* __restrict__ Xb, const float* __restrict__ s,
    const float* __restrict__ Py, const float* __restrict__ ToY,
    const float* __restrict__ y,
    float* __restrict__ r1, float* __restrict__ l1,
    float* __restrict__ Pr, float* __restrict__ Pl,
    float* __restrict__ dots)
{
    __shared__ float yv[RB];
    __shared__ float partR[RB][8];
    __shared__ float partL[RB][8];
    __shared__ float rblk[RB], lblk[RB];

    const int rb = blockIdx.x;
    const int tid = threadIdx.x;
    const int c = tid * 8;
    const int n0 = rb * RB;
    const int wave = tid >> 6;
    if (tid < RB) yv[tid] = y[n0 + tid];
    __syncthreads();

    const size_t pidx = (size_t)rb * DCOLS + c;
    float C[8], Tot[8], sv[8];
    {
        const float4 p0 = *reinterpret_cast<const float4*>(Py + pidx);
        const float4 p1 = *reinterpret_cast<const float4*>(Py + pidx + 4);
        C[0]=p0.x; C[1]=p0.y; C[2]=p0.z; C[3]=p0.w;
        C[4]=p1.x; C[5]=p1.y; C[6]=p1.z; C[7]=p1.w;
        const float4 t0 = *reinterpret_cast<const float4*>(ToY + c);
        const float4 t1 = *reinterpret_cast<const float4*>(ToY + c + 4);
        Tot[0]=t0.x; Tot[1]=t0.y; Tot[2]=t0.z; Tot[3]=t0.w;
        Tot[4]=t1.x; Tot[5]=t1.y; Tot[6]=t1.z; Tot[7]=t1.w;
        const float4 s0 = *reinterpret_cast<const float4*>(s + c);
        const float4 s1 = *reinterpret_cast<const float4*>(s + c + 4);
        sv[0]=s0.x; sv[1]=s0.y; sv[2]=s0.z; sv[3]=s0.w;
        sv[4]=s1.x; sv[5]=s1.y; sv[6]=s1.z; sv[7]=s1.w;
    }

    // ---- phase 1: scan + per-row dots ----
    for (int i = 0; i < RB; ++i) {
        float x[8];
        xload8(Xb, (size_t)(n0 + i) * DCOLS + c, x);
        const float av = yv[i];
        float lp = 0.f, rp = 0.f;
        #pragma unroll
        for (int j = 0; j < 8; ++j) {
            const float xs = x[j] * sv[j];
            lp += xs * C[j];            // exclusive prefix (l-path)
            C[j] += x[j] * av;
            rp += xs * (Tot[j] - C[j]); // suffix (r-path)
        }
        lp = waveReduce(lp);
        rp = waveReduce(rp);
        if ((tid & 63) == 0) { partL[i][wave] = lp; partR[i][wave] = rp; }
    }
    __syncthreads();
    if (tid < RB) {
        float rv = 0.f, lv = 0.f;
        #pragma unroll
        for (int w = 0; w < 8; ++w) { rv += partR[tid][w]; lv += partL[tid][w]; }
        r1[n0 + tid] = rv; l1[n0 + tid] = lv;
        rblk[tid] = rv;    lblk[tid] = lv;
    }
    __syncthreads();

    // fused dots: d0 += y.r1 (this block's rows), d1 += l1.r1
    if (tid < 64) {
        float pd0 = 0.f, pd1 = 0.f;
        if (tid < RB) { pd0 = yv[tid] * rblk[tid]; pd1 = lblk[tid] * rblk[tid]; }
        pd0 = waveReduce(pd0);
        pd1 = waveReduce(pd1);
        if (tid == 0) { atomicAdd(&dots[0], pd0); atomicAdd(&dots[1], pd1); }
    }

    // ---- phase 2: stage-B partials (tile re-read hits L1/L2) ----
    float ar[8], al[8];
    #pragma unroll
    for (int j = 0; j < 8; ++j) { ar[j] = 0.f; al[j] = 0.f; }
    for (int i = 0; i < RB; ++i) {
        float x[8];
        xload8(Xb, (size_t)(n0 + i) * DCOLS + c, x);
        const float rv = rblk[i], lv = lblk[i];
        #pragma unroll
        for (int j = 0; j < 8; ++j) { ar[j] += x[j] * rv; al[j] += x[j] * lv; }
    }
    *reinterpret_cast<float4*>(Pr + pidx)     = make_float4(ar[0], ar[1], ar[2], ar[3]);
    *reinterpret_cast<float4*>(Pr + pidx + 4) = make_float4(ar[4], ar[5], ar[6], ar[7]);
    *reinterpret_cast<float4*>(Pl + pidx)     = make_float4(al[0], al[1], al[2], al[3]);
    *reinterpret_cast<float4*>(Pl + pidx + 4) = make_float4(al[4], al[5], al[6], al[7]);
}

// ---------------- K5: stage-B pass2 -> dots d2,d3 (no r2/l2 materialization) --------
__global__ __launch_bounds__(512) void k5_pass2B(
    const unsigned char* __restrict__ Xb, const float* __restrict__ s,
    const float* __restrict__ Pr, const float* __restrict__ ToR,
    const float* __restrict__ Pl,
    const float* __restrict__ r1v, const float* __restrict__ l1v,
    float* __restrict__ dots)
{
    __shared__ float rv_s[RB], lv_s[RB];
    __shared__ float partR[RB][8];
    __shared__ float partL[RB][8];

    const int rb = blockIdx.x;
    const int tid = threadIdx.x;
    const int c = tid * 8;
    const int n0 = rb * RB;
    const int wave = tid >> 6;
    if (tid < RB) { rv_s[tid] = r1v[n0 + tid]; lv_s[tid] = l1v[n0 + tid]; }
    __syncthreads();

    const size_t pidx = (size_t)rb * DCOLS + c;
    float Cr[8], Cl[8], Tot[8], sv[8];
    {
        const float4 p0 = *reinterpret_cast<const float4*>(Pr + pidx);
        const float4 p1 = *reinterpret_cast<const float4*>(Pr + pidx + 4);
        Cr[0]=p0.x; Cr[1]=p0.y; Cr[2]=p0.z; Cr[3]=p0.w;
        Cr[4]=p1.x; Cr[5]=p1.y; Cr[6]=p1.z; Cr[7]=p1.w;
        const float4 q0 = *reinterpret_cast<const float4*>(Pl + pidx);
        const float4 q1 = *reinterpret_cast<const float4*>(Pl + pidx + 4);
        Cl[0]=q0.x; Cl[1]=q0.y; Cl[2]=q0.z; Cl[3]=q0.w;
        Cl[4]=q1.x; Cl[5]=q1.y; Cl[6]=q1.z; Cl[7]=q1.w;
        const float4 t0 = *reinterpret_cast<const float4*>(ToR + c);
        const float4 t1 = *reinterpret_cast<const float4*>(ToR + c + 4);
        Tot[0]=t0.x; Tot[1]=t0.y; Tot[2]=t0.z; Tot[3]=t0.w;
        Tot[4]=t1.x; Tot[5]=t1.y; Tot[6]=t1.z; Tot[7]=t1.w;
        const float4 s0 = *reinterpret_cast<const float4*>(s + c);
        const float4 s1 = *reinterpret_cast<const float4*>(s + c + 4);
        sv[0]=s0.x; sv[1]=s0.y; sv[2]=s0.z; sv[3]=s0.w;
        sv[4]=s1.x; sv[5]=s1.y; sv[6]=s1.z; sv[7]=s1.w;
    }

    for (int i = 0; i < RB; ++i) {
        float x[8];
        xload8(Xb, (size_t)(n0 + i) * DCOLS + c, x);
        const float rv = rv_s[i], lv = lv_s[i];
        float lp = 0.f, rp = 0.f;
        #pragma unroll
        for (int j = 0; j < 8; ++j) {
            const float xs = x[j] * sv[j];
            lp += xs * Cl[j];            // exclusive prefix of X*l1
            Cl[j] += x[j] * lv;
            Cr[j] += x[j] * rv;
            rp += xs * (Tot[j] - Cr[j]); // suffix of X*r1
        }
        lp = waveReduce(lp);
        rp = waveReduce(rp);
        if ((tid & 63) == 0) { partL[i][wave] = lp; partR[i][wave] = rp; }
    }
    __syncthreads();

    // fused dots: d2 += l1.r2, d3 += l2.r2 over this block's rows
    if (tid < 64) {
        float pd2 = 0.f, pd3 = 0.f;
        if (tid < RB) {
            float r2v = 0.f, l2v = 0.f;
            #pragma unroll
            for (int w = 0; w < 8; ++w) { r2v += partR[tid][w]; l2v += partL[tid][w]; }
            pd2 = lv_s[tid] * r2v;
            pd3 = l2v * r2v;
        }
        pd2 = waveReduce(pd2);
        pd3 = waveReduce(pd3);
        if (tid == 0) { atomicAdd(&dots[2], pd2); atomicAdd(&dots[3], pd3); }
    }
}

// ---------------- final combine ----------------
__global__ __launch_bounds__(64) void finish_kernel(
    const float* __restrict__ dots, const float* __restrict__ a,
    float* __restrict__ out)
{
    if (threadIdx.x == 0) {
        const float z = a[0] * dots[0] + a[1] * dots[1]
                      + a[2] * dots[2] + a[3] * dots[3];
        out[0] = 1.0f - z;
    }
}

extern "C" void kernel_launch(void* const* d_in, const int* in_sizes, int n_in,
                              void* d_out, int out_size, void* d_ws, size_t ws_size,
                              hipStream_t stream)
{
    const float* s = (const float*)d_in[0];   // [DCOLS]
    const float* X = (const float*)d_in[1];   // [NROWS, DCOLS]
    const float* y = (const float*)d_in[2];   // [NROWS]
    const float* a = (const float*)d_in[3];   // [4]
    float* out = (float*)d_out;

    char* ws = (char*)d_ws;
    const size_t XBSZ = (size_t)NROWS * DCOLS * 2;   // reserve 2 B/elem (codec-agnostic)
    const size_t PCNT = (size_t)NBLK * DCOLS;        // 1M floats per partial array
    unsigned char* Xb = (unsigned char*)ws;
    float* Py   = (float*)(ws + XBSZ);
    float* Pr   = Py + PCNT;
    float* Pl   = Pr + PCNT;
    float* ToY  = Pl + PCNT;
    float* ToR  = ToY + DCOLS;
    float* ToL  = ToR + DCOLS;
    float* r1   = ToL + DCOLS;
    float* l1   = r1 + NROWS;
    float* dots = l1 + NROWS;                        // [4]

    // stage A
    k1_conv_partial<<<dim3(NBLK, 4), dim3(256), 0, stream>>>(X, y, Xb, Py);
    prefix_kernel<0><<<dim3(DCOLS / 256), dim3(256), 0, stream>>>(
        Py, ToY, nullptr, nullptr, dots);
    k3_pass2A_partialB<<<dim3(NBLK), dim3(512), 0, stream>>>(
        Xb, s, Py, ToY, y, r1, l1, Pr, Pl, dots);

    // stage B
    prefix_kernel<1><<<dim3(DCOLS / 256), dim3(256), 0, stream>>>(
        Pr, ToR, Pl, ToL, dots);
    k5_pass2B<<<dim3(NBLK), dim3(512), 0, stream>>>(
        Xb, s, Pr, ToR, Pl, r1, l1, dots);

    // combine
    finish_kernel<<<dim3(1), dim3(64), 0, stream>>>(dots, a, out);
}